// Round 4
// baseline (523.970 us; speedup 1.0000x reference)
//
#include <hip/hip_runtime.h>
#include <math.h>

// Problem constants: N=100000, E=1600000, D_IN=D_OUT=128
#define D 128
constexpr float BN_EPS = 1e-5f;
typedef unsigned long long ull;

// bf16 helpers (manual, RNE) ------------------------------------------------
__device__ __forceinline__ unsigned f2bf_rne(float f) {
    unsigned u = __float_as_uint(f);
    return (u + 0x7FFFu + ((u >> 16) & 1u)) >> 16;
}
__device__ __forceinline__ float bf_lo(unsigned u) { return __uint_as_float(u << 16); }
__device__ __forceinline__ float bf_hi(unsigned u) { return __uint_as_float(u & 0xFFFF0000u); }

// ---------------------------------------------------------------------------
// GEMM y = x @ W, epilogue packs y to bf16 words (yb [n,64], word w = cols
// 2w,2w+1).  Associativity: h = (A x) W = A (x W), so we do the dense GEMM
// FIRST and the SpMM gathers y rows -- the 51.2MB agg buffer disappears.
// Block = 256 threads -> 32 rows x 128 cols; W(64KB)+A(16KB) LDS = 2 blk/CU.
// ---------------------------------------------------------------------------
__global__ __launch_bounds__(256) void gemm_pack_kernel(
    const float* __restrict__ A,
    const float* __restrict__ W,
    unsigned* __restrict__ yb,
    int n)
{
    __shared__ float sW[128 * 128];
    __shared__ float sA[32][128];

    const int tid = threadIdx.x;

    const float4* W4  = (const float4*)W;
    float4*       sW4 = (float4*)sW;
#pragma unroll
    for (int i = 0; i < 16; i++) sW4[tid + 256 * i] = W4[tid + 256 * i];

    const int row0 = blockIdx.x * 32;
    const float4* A4  = (const float4*)(A + (size_t)row0 * D);
    float4*       sA4 = (float4*)&sA[0][0];
#pragma unroll
    for (int i = 0; i < 4; i++) {
        int idx = tid + 256 * i;
        sA4[idx] = ((size_t)row0 * D + (size_t)idx * 4 < (size_t)n * D)
                       ? A4[idx] : make_float4(0.f, 0.f, 0.f, 0.f);
    }
    __syncthreads();

    const int tx = tid & 31;   // 32 col-groups of 4
    const int ty = tid >> 5;   // 8 row slots (rows ty, ty+8, ty+16, ty+24)
    const int c0 = tx * 4;

    float acc[4][4] = {};
    for (int k0 = 0; k0 < 128; k0 += 4) {
        float4 a[4];
#pragma unroll
        for (int j = 0; j < 4; j++)
            a[j] = *(const float4*)&sA[ty + 8 * j][k0];
#pragma unroll
        for (int kk = 0; kk < 4; kk++) {
            const float4 w = *(const float4*)&sW[(k0 + kk) * 128 + c0];
            const float ak[4] = { kk == 0 ? a[0].x : kk == 1 ? a[0].y : kk == 2 ? a[0].z : a[0].w,
                                  kk == 0 ? a[1].x : kk == 1 ? a[1].y : kk == 2 ? a[1].z : a[1].w,
                                  kk == 0 ? a[2].x : kk == 1 ? a[2].y : kk == 2 ? a[2].z : a[2].w,
                                  kk == 0 ? a[3].x : kk == 1 ? a[3].y : kk == 2 ? a[3].z : a[3].w };
#pragma unroll
            for (int j = 0; j < 4; j++) {
                acc[j][0] += ak[j] * w.x;
                acc[j][1] += ak[j] * w.y;
                acc[j][2] += ak[j] * w.z;
                acc[j][3] += ak[j] * w.w;
            }
        }
    }

#pragma unroll
    for (int j = 0; j < 4; j++) {
        const int row = row0 + ty + 8 * j;
        if (row < n) {
            uint2 o;
            o.x = f2bf_rne(acc[j][0]) | (f2bf_rne(acc[j][1]) << 16);
            o.y = f2bf_rne(acc[j][2]) | (f2bf_rne(acc[j][3]) << 16);
            ((uint2*)(yb + (size_t)row * 64))[tx] = o;
        }
    }
}

// ---------------------------------------------------------------------------
// CSR build step 1: histogram of edge destinations.
// ---------------------------------------------------------------------------
__global__ __launch_bounds__(256) void hist_kernel(
    const int* __restrict__ edst, int* __restrict__ cnt, int E)
{
    int e = blockIdx.x * blockDim.x + threadIdx.x;
    if (e < E) atomicAdd(&cnt[edst[e]], 1);
}

// ---------------------------------------------------------------------------
// Multi-block exclusive scan of cnt[n] -> rowptr[n] (3 passes).
// ---------------------------------------------------------------------------
__global__ __launch_bounds__(256) void scan_part_kernel(
    const int* __restrict__ cnt, int* __restrict__ bsum, int n)
{
    __shared__ int red[256];
    const int tid = threadIdx.x;
    const int base = blockIdx.x * 1024 + tid * 4;
    int s = 0;
#pragma unroll
    for (int i = 0; i < 4; i++) { int idx = base + i; if (idx < n) s += cnt[idx]; }
    red[tid] = s;
    __syncthreads();
    for (int off = 128; off > 0; off >>= 1) {
        if (tid < off) red[tid] += red[tid + off];
        __syncthreads();
    }
    if (tid == 0) bsum[blockIdx.x] = red[0];
}

__global__ __launch_bounds__(256) void scan_mid_kernel(int* __restrict__ bsum, int nb)
{
    __shared__ int sm[256];
    const int tid = threadIdx.x;
    int v = (tid < nb) ? bsum[tid] : 0;
    sm[tid] = v;
    __syncthreads();
    for (int off = 1; off < 256; off <<= 1) {
        int t = (tid >= off) ? sm[tid - off] : 0;
        __syncthreads();
        sm[tid] += t;
        __syncthreads();
    }
    if (tid < nb) bsum[tid] = sm[tid] - v;   // exclusive
}

__global__ __launch_bounds__(256) void scan_final_kernel(
    const int* __restrict__ cnt, const int* __restrict__ bsum,
    int* __restrict__ rowptr, int n)
{
    __shared__ int part[256];
    const int tid = threadIdx.x;
    const int base = blockIdx.x * 1024 + tid * 4;
    int v[4];
    int s = 0;
#pragma unroll
    for (int i = 0; i < 4; i++) {
        int idx = base + i;
        v[i] = (idx < n) ? cnt[idx] : 0;
        s += v[i];
    }
    part[tid] = s;
    __syncthreads();
    for (int off = 1; off < 256; off <<= 1) {
        int t = (tid >= off) ? part[tid - off] : 0;
        __syncthreads();
        part[tid] += t;
        __syncthreads();
    }
    int run = bsum[blockIdx.x] + part[tid] - s;   // exclusive prefix
#pragma unroll
    for (int i = 0; i < 4; i++) {
        int idx = base + i;
        if (idx < n) rowptr[idx] = run;
        run += v[i];
    }
}

// ---------------------------------------------------------------------------
// CSR build step 3: scatter edges into CSR order via 8B atomicExch.
// Device-scope atomics write through at OP granularity (round-1 counter
// evidence: WRITE_SIZE == 8B x #atomics), avoiding the 64B/edge line-RMW
// writeback amplification that plain 8B stores suffer across non-coherent
// per-XCD L2s (round-3: WRITE_SIZE was E*64B).
// rowptr doubles as the fill cursor: afterwards rowptr[d] == end of row d.
// ---------------------------------------------------------------------------
__global__ __launch_bounds__(256) void scatter_kernel(
    const int* __restrict__ esrc, const int* __restrict__ edst,
    const float* __restrict__ evals,
    int* __restrict__ rowptr, ull* __restrict__ csr, int E)
{
    int e = blockIdx.x * blockDim.x + threadIdx.x;
    if (e < E) {
        int d = edst[e];
        int pos = atomicAdd(&rowptr[d], 1);
        ull packed = ((ull)__float_as_uint(evals[e]) << 32) | (unsigned)esrc[e];
        atomicExch(&csr[pos], packed);
    }
}

// ---------------------------------------------------------------------------
// CSR SpMM: h[dst] = sum val * y[src]  (bf16 y gather, fp32 accumulate).
// One wave per dst row; lane handles 2 cols (one packed bf16x2 word,
// 4B/lane = 256B/row). 4-edge unroll for ILP. Output -> d_out.
// ---------------------------------------------------------------------------
__global__ __launch_bounds__(256) void spmm_csr_bf16_kernel(
    const unsigned* __restrict__ yb,
    const int* __restrict__ rowptr,   // post-scatter (end-pointer) form
    const ull* __restrict__ csr,
    float* __restrict__ h, int n)
{
    int wave = (blockIdx.x * blockDim.x + threadIdx.x) >> 6;
    int lane = threadIdx.x & 63;
    if (wave >= n) return;
    int start = (wave == 0) ? 0 : rowptr[wave - 1];
    int end   = rowptr[wave];

    float ax = 0.f, ay = 0.f;
    int e = start;
    for (; e + 3 < end; e += 4) {
        ull e0 = csr[e], e1 = csr[e + 1], e2 = csr[e + 2], e3 = csr[e + 3];
        unsigned u0 = yb[(size_t)(unsigned)e0 * 64 + lane];
        unsigned u1 = yb[(size_t)(unsigned)e1 * 64 + lane];
        unsigned u2 = yb[(size_t)(unsigned)e2 * 64 + lane];
        unsigned u3 = yb[(size_t)(unsigned)e3 * 64 + lane];
        float v0 = __uint_as_float((unsigned)(e0 >> 32));
        float v1 = __uint_as_float((unsigned)(e1 >> 32));
        float v2 = __uint_as_float((unsigned)(e2 >> 32));
        float v3 = __uint_as_float((unsigned)(e3 >> 32));
        ax += v0 * bf_lo(u0) + v1 * bf_lo(u1) + v2 * bf_lo(u2) + v3 * bf_lo(u3);
        ay += v0 * bf_hi(u0) + v1 * bf_hi(u1) + v2 * bf_hi(u2) + v3 * bf_hi(u3);
    }
    for (; e < end; e++) {
        ull ed = csr[e];
        unsigned u = yb[(size_t)(unsigned)ed * 64 + lane];
        float v = __uint_as_float((unsigned)(ed >> 32));
        ax += v * bf_lo(u);
        ay += v * bf_hi(u);
    }
    ((float2*)(h + (size_t)wave * D))[lane] = make_float2(ax, ay);
}

// ---------------------------------------------------------------------------
// Column stats of h: sum and sum of squares per column.
// 256 blocks x 256 threads = 2 rows x 128 cols per block-iteration.
// ---------------------------------------------------------------------------
__global__ __launch_bounds__(256) void stats_kernel(
    const float* __restrict__ h,
    float* __restrict__ stats,   // [0..127]=sum, [128..255]=sumsq
    int n)
{
    __shared__ float ssum[256];
    __shared__ float ssq[256];
    const int tid  = threadIdx.x;
    const int col  = tid & 127;
    const int half = tid >> 7;

    float s = 0.f, q = 0.f;
    for (int r = blockIdx.x * 2 + half; r < n; r += gridDim.x * 2) {
        const float v = h[(size_t)r * D + col];
        s += v;
        q += v * v;
    }
    ssum[tid] = s;
    ssq[tid]  = q;
    __syncthreads();
    if (tid < 128) {
        atomicAdd(&stats[col],       ssum[tid] + ssum[tid + 128]);
        atomicAdd(&stats[128 + col], ssq[tid] + ssq[tid + 128]);
    }
}

// ---------------------------------------------------------------------------
// In-place BatchNorm apply. Linear bias cancels under BN -> omitted.
// ---------------------------------------------------------------------------
__global__ __launch_bounds__(256) void bn_apply_kernel(
    float* __restrict__ h,
    const float* __restrict__ stats,
    const float* __restrict__ gamma,
    const float* __restrict__ beta,
    int n)
{
    __shared__ float s_scale[128];
    __shared__ float s_shift[128];
    const int tid = threadIdx.x;
    if (tid < 128) {
        const float invn = 1.0f / (float)n;
        const float mean = stats[tid] * invn;
        const float var  = stats[128 + tid] * invn - mean * mean;
        const float inv  = rsqrtf(var + BN_EPS);
        const float g    = gamma[tid] * inv;
        s_scale[tid] = g;
        s_shift[tid] = beta[tid] - mean * g;
    }
    __syncthreads();

    float4* h4 = (float4*)h;
    const size_t total = (size_t)n * D / 4;
    const size_t stride = (size_t)gridDim.x * blockDim.x;
    for (size_t i = (size_t)blockIdx.x * blockDim.x + tid; i < total; i += stride) {
        float4 v = h4[i];
        const int c = (int)((i * 4) & (D - 1));
        v.x = v.x * s_scale[c]     + s_shift[c];
        v.y = v.y * s_scale[c + 1] + s_shift[c + 1];
        v.z = v.z * s_scale[c + 2] + s_shift[c + 2];
        v.w = v.w * s_scale[c + 3] + s_shift[c + 3];
        h4[i] = v;
    }
}

// ---------------------------------------------------------------------------
// Fallback (ws too small): atomic-scatter SpMM in fp32 + GEMM w/ stats.
// ---------------------------------------------------------------------------
__global__ __launch_bounds__(256) void spmm_atomic_kernel(
    const float* __restrict__ x,
    const int* __restrict__ esrc, const int* __restrict__ edst,
    const float* __restrict__ eval, float* __restrict__ agg, int E)
{
    int wave  = (blockIdx.x * blockDim.x + threadIdx.x) >> 6;
    int lane  = threadIdx.x & 63;
    int nwave = (gridDim.x * blockDim.x) >> 6;
    for (int e = wave; e < E; e += nwave) {
        int   s = esrc[e];
        int   d = edst[e];
        float v = eval[e];
        const float2 xv = ((const float2*)(x + (size_t)s * D))[lane];
        float* ar = agg + (size_t)d * D + lane * 2;
        atomicAdd(ar,     xv.x * v);
        atomicAdd(ar + 1, xv.y * v);
    }
}

__global__ __launch_bounds__(256) void gemm_stats_kernel(
    const float* __restrict__ A,
    const float* __restrict__ W,
    float* __restrict__ h,
    float* __restrict__ stats,
    int n)
{
    __shared__ float sW[128 * 128];
    __shared__ float sA[32][128];
    const int tid = threadIdx.x;
    const float4* W4  = (const float4*)W;
    float4*       sW4 = (float4*)sW;
#pragma unroll
    for (int i = 0; i < 16; i++) sW4[tid + 256 * i] = W4[tid + 256 * i];
    const int row0 = blockIdx.x * 32;
    const float4* A4  = (const float4*)(A + (size_t)row0 * D);
    float4*       sA4 = (float4*)&sA[0][0];
#pragma unroll
    for (int i = 0; i < 4; i++) {
        int idx = tid + 256 * i;
        sA4[idx] = ((size_t)row0 * D + (size_t)idx * 4 < (size_t)n * D)
                       ? A4[idx] : make_float4(0.f, 0.f, 0.f, 0.f);
    }
    __syncthreads();
    const int tx = tid & 31, ty = tid >> 5, c0 = tx * 4;
    float acc[4][4] = {};
    for (int k = 0; k < 128; k++) {
        const float4 w = *(const float4*)&sW[k * 128 + c0];
#pragma unroll
        for (int j = 0; j < 4; j++) {
            const float a = sA[ty + 8 * j][k];
            acc[j][0] += a * w.x; acc[j][1] += a * w.y;
            acc[j][2] += a * w.z; acc[j][3] += a * w.w;
        }
    }
#pragma unroll
    for (int j = 0; j < 4; j++) {
        const int row = row0 + ty + 8 * j;
        if (row < n)
            *(float4*)&h[(size_t)row * D + c0] =
                make_float4(acc[j][0], acc[j][1], acc[j][2], acc[j][3]);
    }
    __syncthreads();
    float* csum = &sA[0][0];
    float* csq  = csum + 128;
    if (tid < 128) { csum[tid] = 0.f; csq[tid] = 0.f; }
    __syncthreads();
#pragma unroll
    for (int c = 0; c < 4; c++) {
        float s = 0.f, q = 0.f;
#pragma unroll
        for (int j = 0; j < 4; j++) { s += acc[j][c]; q += acc[j][c] * acc[j][c]; }
        atomicAdd(&csum[c0 + c], s);
        atomicAdd(&csq[c0 + c], q);
    }
    __syncthreads();
    if (tid < 128) {
        atomicAdd(&stats[tid],       csum[tid]);
        atomicAdd(&stats[128 + tid], csq[tid]);
    }
}

// ---------------------------------------------------------------------------
extern "C" void kernel_launch(void* const* d_in, const int* in_sizes, int n_in,
                              void* d_out, int out_size, void* d_ws, size_t ws_size,
                              hipStream_t stream)
{
    const float* x     = (const float*)d_in[0];
    const int*   esrc  = (const int*)d_in[1];
    const int*   edst  = (const int*)d_in[2];
    const float* evals = (const float*)d_in[3];
    const float* W     = (const float*)d_in[4];
    // d_in[5] = bias: unused — cancels exactly under BatchNorm.
    const float* gamma = (const float*)d_in[6];
    const float* beta  = (const float*)d_in[7];
    float* out = (float*)d_out;

    const int n = in_sizes[0] / D;   // 100000
    const int E = in_sizes[1];       // 1600000

    // Workspace (word-indexed):
    //   yb     [n*64] u32   25.6 MB  (packed bf16 y = x@W)
    //   cnt    [n]          0.4 MB   (zeroed)
    //   stats  [256]                 (zeroed, same memset)
    //   rowptr [n]
    //   bsum   [128]
    //   csr    [E] ull      12.8 MB  (8B-aligned: word offset is even)
    unsigned* yb     = (unsigned*)d_ws;
    int*      cnt    = (int*)(yb + (size_t)n * 64);
    float*    stats  = (float*)(cnt + n);
    int*      rowptr = (int*)(stats + 256);
    int*      bsum   = rowptr + n;
    size_t    csr_off = (size_t)n * 64 + n + 256 + n + 128;
    csr_off += (csr_off & 1);                      // 8B alignment
    ull*      csr    = (ull*)((unsigned*)d_ws + csr_off);
    const size_t need = csr_off * 4 + (size_t)E * 8;

    const int nscan = (n + 1023) / 1024;   // 98 blocks (<=256 required)

    if (ws_size >= need && nscan <= 256) {
        hipMemsetAsync(cnt, 0, ((size_t)n + 256) * 4, stream);
        gemm_pack_kernel<<<(n + 31) / 32, 256, 0, stream>>>(x, W, yb, n);
        hist_kernel<<<(E + 255) / 256, 256, 0, stream>>>(edst, cnt, E);
        scan_part_kernel<<<nscan, 256, 0, stream>>>(cnt, bsum, n);
        scan_mid_kernel<<<1, 256, 0, stream>>>(bsum, nscan);
        scan_final_kernel<<<nscan, 256, 0, stream>>>(cnt, bsum, rowptr, n);
        scatter_kernel<<<(E + 255) / 256, 256, 0, stream>>>(
            esrc, edst, evals, rowptr, csr, E);
        spmm_csr_bf16_kernel<<<(n + 3) / 4, 256, 0, stream>>>(
            yb, rowptr, csr, out, n);
        stats_kernel<<<256, 256, 0, stream>>>(out, stats, n);
        bn_apply_kernel<<<2048, 256, 0, stream>>>(out, stats, gamma, beta, n);
    } else {
        // fallback: fp32 atomic-scatter path
        float* agg = (float*)d_ws;
        float* st  = agg + (size_t)n * D;
        hipMemsetAsync(d_ws, 0, ((size_t)n * D + 256) * 4, stream);
        spmm_atomic_kernel<<<4096, 256, 0, stream>>>(x, esrc, edst, evals, agg, E);
        gemm_stats_kernel<<<(n + 31) / 32, 256, 0, stream>>>(agg, W, out, st, n);
        bn_apply_kernel<<<2048, 256, 0, stream>>>(out, st, gamma, beta, n);
    }
}

// Round 5
// 419.290 us; speedup vs baseline: 1.2497x; 1.2497x over previous
//
#include <hip/hip_runtime.h>
#include <math.h>

// Problem constants: N=100000, E=1600000, D_IN=D_OUT=128
#define D 128
#define BSHIFT 9              // 512 dst rows per bucket
#define BROWS 512
#define TILE 8192             // edges per binA workgroup
constexpr float BN_EPS = 1e-5f;
typedef unsigned long long ull;

// bf16 helpers (manual, RNE) ------------------------------------------------
__device__ __forceinline__ unsigned f2bf_rne(float f) {
    unsigned u = __float_as_uint(f);
    return (u + 0x7FFFu + ((u >> 16) & 1u)) >> 16;
}
__device__ __forceinline__ float bf_lo(unsigned u) { return __uint_as_float(u << 16); }
__device__ __forceinline__ float bf_hi(unsigned u) { return __uint_as_float(u & 0xFFFF0000u); }

// ---------------------------------------------------------------------------
// GEMM y = x @ W, epilogue packs y to bf16 words (yb [n,64]).
// Associativity: h = (A x) W = A (x W) -> dense GEMM first, SpMM gathers y.
// ---------------------------------------------------------------------------
__global__ __launch_bounds__(256) void gemm_pack_kernel(
    const float* __restrict__ A,
    const float* __restrict__ W,
    unsigned* __restrict__ yb,
    int n)
{
    __shared__ float sW[128 * 128];
    __shared__ float sA[32][128];

    const int tid = threadIdx.x;

    const float4* W4  = (const float4*)W;
    float4*       sW4 = (float4*)sW;
#pragma unroll
    for (int i = 0; i < 16; i++) sW4[tid + 256 * i] = W4[tid + 256 * i];

    const int row0 = blockIdx.x * 32;
    const float4* A4  = (const float4*)(A + (size_t)row0 * D);
    float4*       sA4 = (float4*)&sA[0][0];
#pragma unroll
    for (int i = 0; i < 4; i++) {
        int idx = tid + 256 * i;
        sA4[idx] = ((size_t)row0 * D + (size_t)idx * 4 < (size_t)n * D)
                       ? A4[idx] : make_float4(0.f, 0.f, 0.f, 0.f);
    }
    __syncthreads();

    const int tx = tid & 31;
    const int ty = tid >> 5;
    const int c0 = tx * 4;

    float acc[4][4] = {};
    for (int k0 = 0; k0 < 128; k0 += 4) {
        float4 a[4];
#pragma unroll
        for (int j = 0; j < 4; j++)
            a[j] = *(const float4*)&sA[ty + 8 * j][k0];
#pragma unroll
        for (int kk = 0; kk < 4; kk++) {
            const float4 w = *(const float4*)&sW[(k0 + kk) * 128 + c0];
            const float ak[4] = { kk == 0 ? a[0].x : kk == 1 ? a[0].y : kk == 2 ? a[0].z : a[0].w,
                                  kk == 0 ? a[1].x : kk == 1 ? a[1].y : kk == 2 ? a[1].z : a[1].w,
                                  kk == 0 ? a[2].x : kk == 1 ? a[2].y : kk == 2 ? a[2].z : a[2].w,
                                  kk == 0 ? a[3].x : kk == 1 ? a[3].y : kk == 2 ? a[3].z : a[3].w };
#pragma unroll
            for (int j = 0; j < 4; j++) {
                acc[j][0] += ak[j] * w.x;
                acc[j][1] += ak[j] * w.y;
                acc[j][2] += ak[j] * w.z;
                acc[j][3] += ak[j] * w.w;
            }
        }
    }

#pragma unroll
    for (int j = 0; j < 4; j++) {
        const int row = row0 + ty + 8 * j;
        if (row < n) {
            uint2 o;
            o.x = f2bf_rne(acc[j][0]) | (f2bf_rne(acc[j][1]) << 16);
            o.y = f2bf_rne(acc[j][2]) | (f2bf_rne(acc[j][3]) << 16);
            ((uint2*)(yb + (size_t)row * 64))[tx] = o;
        }
    }
}

// ---------------------------------------------------------------------------
// binA: coarse bucket sort. Each wg owns edges [wg*TILE, ...) and a PRIVATE
// slice of the record buffer (only this wg writes it -> lines fill densely in
// one XCD's L2 -> writeback ~= payload, not 64B/edge as in round-3/4 scatter).
// Record: .x = dstLow(9b) | src<<9 (17b), .y = val bits.
// Also emits per-(wg,bucket) offset table and global bucket counts.
// ---------------------------------------------------------------------------
__global__ __launch_bounds__(256) void binA_kernel(
    const int* __restrict__ esrc, const int* __restrict__ edst,
    const float* __restrict__ evals,
    uint2* __restrict__ slices,        // [nwgA * TILE]
    int* __restrict__ ofs,             // [nwgA * (B+1)]
    int* __restrict__ bucket_cnt,      // [B], pre-zeroed
    int B, int E)
{
    __shared__ int h[256];
    __shared__ int ps[256];
    __shared__ int cur[256];

    const int tid = threadIdx.x;
    const int wg  = blockIdx.x;
    const int e0  = wg * TILE;
    const int e1  = min(e0 + TILE, E);

    h[tid] = 0;
    __syncthreads();

    // phase 1: bucket histogram
    for (int e = e0 + tid; e < e1; e += 256)
        atomicAdd(&h[edst[e] >> BSHIFT], 1);
    __syncthreads();

    // phase 2: exclusive scan over B (<=256) buckets (Hillis-Steele)
    const int v = h[tid];
    ps[tid] = v;
    __syncthreads();
    for (int off = 1; off < 256; off <<= 1) {
        int t = (tid >= off) ? ps[tid - off] : 0;
        __syncthreads();
        if (tid >= off) ps[tid] += t;
        __syncthreads();
    }
    const int excl = ps[tid] - v;
    if (tid < B) {
        cur[tid] = excl;
        ofs[(size_t)wg * (B + 1) + tid] = excl;
        if (v) atomicAdd(&bucket_cnt[tid], v);
    }
    if (tid == 0) ofs[(size_t)wg * (B + 1) + B] = e1 - e0;
    __syncthreads();

    // phase 3: place records into private slice (edst re-read is L2-hot)
    uint2* slice = slices + (size_t)wg * TILE;
    for (int e = e0 + tid; e < e1; e += 256) {
        int d = edst[e];
        int b = d >> BSHIFT;
        int p = atomicAdd(&cur[b], 1);
        uint2 rec;
        rec.x = (unsigned)(d & (BROWS - 1)) | ((unsigned)esrc[e] << BSHIFT);
        rec.y = __float_as_uint(evals[e]);
        slice[p] = rec;
    }
}

// ---------------------------------------------------------------------------
// Exclusive scan of bucket_cnt[B] -> bucket_base[B]. One block, B<=256.
// ---------------------------------------------------------------------------
__global__ __launch_bounds__(256) void bucket_scan_kernel(
    const int* __restrict__ bucket_cnt, int* __restrict__ bucket_base, int B)
{
    __shared__ int ps[256];
    const int tid = threadIdx.x;
    const int v = (tid < B) ? bucket_cnt[tid] : 0;
    ps[tid] = v;
    __syncthreads();
    for (int off = 1; off < 256; off <<= 1) {
        int t = (tid >= off) ? ps[tid - off] : 0;
        __syncthreads();
        if (tid >= off) ps[tid] += t;
        __syncthreads();
    }
    if (tid < B) bucket_base[tid] = ps[tid] - v;
}

// ---------------------------------------------------------------------------
// binB: one wg per bucket. Gathers the bucket's runs from all slices (run
// bounds from ofs table), LDS-histograms the 512 in-bucket rows, LDS-scans,
// writes global end-form rowptr, then scatters records into the bucket's
// PRIVATE csr window (dense single-XCD writes). Second run read is L2-hot.
// ---------------------------------------------------------------------------
__global__ __launch_bounds__(256) void binB_kernel(
    const uint2* __restrict__ slices,
    const int* __restrict__ ofs,
    const int* __restrict__ bucket_base,
    int* __restrict__ rowptr,          // [n], end-form
    ull* __restrict__ csr,             // [E]
    int B, int nwgA, int n)
{
    __shared__ int hist[BROWS];
    __shared__ int ps[256];
    __shared__ int curs[BROWS];

    const int tid  = threadIdx.x;
    const int b    = blockIdx.x;
    const int wv   = tid >> 6;
    const int lane = tid & 63;
    const int bbase = bucket_base[b];
    const int row0  = b << BSHIFT;

    hist[tid] = 0;
    hist[tid + 256] = 0;
    __syncthreads();

    // phase 1: in-bucket row histogram over this bucket's runs
    for (int wg = wv; wg < nwgA; wg += 4) {
        const int s = ofs[(size_t)wg * (B + 1) + b];
        const int e = ofs[(size_t)wg * (B + 1) + b + 1];
        const uint2* run = slices + (size_t)wg * TILE;
        for (int i = s + lane; i < e; i += 64)
            atomicAdd(&hist[run[i].x & (BROWS - 1)], 1);
    }
    __syncthreads();

    // phase 2: scan 512 rows with 256 threads (pair per thread)
    const int a0 = hist[2 * tid];
    const int a1 = hist[2 * tid + 1];
    ps[tid] = a0 + a1;
    __syncthreads();
    for (int off = 1; off < 256; off <<= 1) {
        int t = (tid >= off) ? ps[tid - off] : 0;
        __syncthreads();
        if (tid >= off) ps[tid] += t;
        __syncthreads();
    }
    const int pairExcl = ps[tid] - (a0 + a1);
    const int r0 = row0 + 2 * tid;
    const int r1 = r0 + 1;
    if (r0 < n) rowptr[r0] = bbase + pairExcl + a0;        // end of row r0
    if (r1 < n) rowptr[r1] = bbase + pairExcl + a0 + a1;   // end of row r1
    curs[2 * tid]     = bbase + pairExcl;                  // start of row r0
    curs[2 * tid + 1] = bbase + pairExcl + a0;             // start of row r1
    __syncthreads();

    // phase 3: scatter into final CSR positions (bucket-private window)
    for (int wg = wv; wg < nwgA; wg += 4) {
        const int s = ofs[(size_t)wg * (B + 1) + b];
        const int e = ofs[(size_t)wg * (B + 1) + b + 1];
        const uint2* run = slices + (size_t)wg * TILE;
        for (int i = s + lane; i < e; i += 64) {
            uint2 r = run[i];
            int pos = atomicAdd(&curs[r.x & (BROWS - 1)], 1);
            csr[pos] = ((ull)r.y << 32) | (r.x >> BSHIFT);
        }
    }
}

// ---------------------------------------------------------------------------
// CSR SpMM: h[dst] = sum val * y[src]  (bf16 y gather, fp32 accumulate).
// One wave per dst row; lane handles 2 cols. 4-edge unroll. Output -> d_out.
// ---------------------------------------------------------------------------
__global__ __launch_bounds__(256) void spmm_csr_bf16_kernel(
    const unsigned* __restrict__ yb,
    const int* __restrict__ rowptr,   // end-form
    const ull* __restrict__ csr,
    float* __restrict__ h, int n)
{
    int wave = (blockIdx.x * blockDim.x + threadIdx.x) >> 6;
    int lane = threadIdx.x & 63;
    if (wave >= n) return;
    int start = (wave == 0) ? 0 : rowptr[wave - 1];
    int end   = rowptr[wave];

    float ax = 0.f, ay = 0.f;
    int e = start;
    for (; e + 3 < end; e += 4) {
        ull e0 = csr[e], e1 = csr[e + 1], e2 = csr[e + 2], e3 = csr[e + 3];
        unsigned u0 = yb[(size_t)(unsigned)e0 * 64 + lane];
        unsigned u1 = yb[(size_t)(unsigned)e1 * 64 + lane];
        unsigned u2 = yb[(size_t)(unsigned)e2 * 64 + lane];
        unsigned u3 = yb[(size_t)(unsigned)e3 * 64 + lane];
        float v0 = __uint_as_float((unsigned)(e0 >> 32));
        float v1 = __uint_as_float((unsigned)(e1 >> 32));
        float v2 = __uint_as_float((unsigned)(e2 >> 32));
        float v3 = __uint_as_float((unsigned)(e3 >> 32));
        ax += v0 * bf_lo(u0) + v1 * bf_lo(u1) + v2 * bf_lo(u2) + v3 * bf_lo(u3);
        ay += v0 * bf_hi(u0) + v1 * bf_hi(u1) + v2 * bf_hi(u2) + v3 * bf_hi(u3);
    }
    for (; e < end; e++) {
        ull ed = csr[e];
        unsigned u = yb[(size_t)(unsigned)ed * 64 + lane];
        float v = __uint_as_float((unsigned)(ed >> 32));
        ax += v * bf_lo(u);
        ay += v * bf_hi(u);
    }
    ((float2*)(h + (size_t)wave * D))[lane] = make_float2(ax, ay);
}

// ---------------------------------------------------------------------------
// Column stats of h.
// ---------------------------------------------------------------------------
__global__ __launch_bounds__(256) void stats_kernel(
    const float* __restrict__ h,
    float* __restrict__ stats,   // [0..127]=sum, [128..255]=sumsq
    int n)
{
    __shared__ float ssum[256];
    __shared__ float ssq[256];
    const int tid  = threadIdx.x;
    const int col  = tid & 127;
    const int half = tid >> 7;

    float s = 0.f, q = 0.f;
    for (int r = blockIdx.x * 2 + half; r < n; r += gridDim.x * 2) {
        const float v = h[(size_t)r * D + col];
        s += v;
        q += v * v;
    }
    ssum[tid] = s;
    ssq[tid]  = q;
    __syncthreads();
    if (tid < 128) {
        atomicAdd(&stats[col],       ssum[tid] + ssum[tid + 128]);
        atomicAdd(&stats[128 + col], ssq[tid] + ssq[tid + 128]);
    }
}

// ---------------------------------------------------------------------------
// In-place BatchNorm apply. Linear bias cancels under BN -> omitted.
// ---------------------------------------------------------------------------
__global__ __launch_bounds__(256) void bn_apply_kernel(
    float* __restrict__ h,
    const float* __restrict__ stats,
    const float* __restrict__ gamma,
    const float* __restrict__ beta,
    int n)
{
    __shared__ float s_scale[128];
    __shared__ float s_shift[128];
    const int tid = threadIdx.x;
    if (tid < 128) {
        const float invn = 1.0f / (float)n;
        const float mean = stats[tid] * invn;
        const float var  = stats[128 + tid] * invn - mean * mean;
        const float inv  = rsqrtf(var + BN_EPS);
        const float g    = gamma[tid] * inv;
        s_scale[tid] = g;
        s_shift[tid] = beta[tid] - mean * g;
    }
    __syncthreads();

    float4* h4 = (float4*)h;
    const size_t total = (size_t)n * D / 4;
    const size_t stride = (size_t)gridDim.x * blockDim.x;
    for (size_t i = (size_t)blockIdx.x * blockDim.x + tid; i < total; i += stride) {
        float4 v = h4[i];
        const int c = (int)((i * 4) & (D - 1));
        v.x = v.x * s_scale[c]     + s_shift[c];
        v.y = v.y * s_scale[c + 1] + s_shift[c + 1];
        v.z = v.z * s_scale[c + 2] + s_shift[c + 2];
        v.w = v.w * s_scale[c + 3] + s_shift[c + 3];
        h4[i] = v;
    }
}

// ---------------------------------------------------------------------------
// Fallback (ws too small / shape mismatch): atomic SpMM + GEMM w/ stats.
// ---------------------------------------------------------------------------
__global__ __launch_bounds__(256) void spmm_atomic_kernel(
    const float* __restrict__ x,
    const int* __restrict__ esrc, const int* __restrict__ edst,
    const float* __restrict__ eval, float* __restrict__ agg, int E)
{
    int wave  = (blockIdx.x * blockDim.x + threadIdx.x) >> 6;
    int lane  = threadIdx.x & 63;
    int nwave = (gridDim.x * blockDim.x) >> 6;
    for (int e = wave; e < E; e += nwave) {
        int   s = esrc[e];
        int   d = edst[e];
        float v = eval[e];
        const float2 xv = ((const float2*)(x + (size_t)s * D))[lane];
        float* ar = agg + (size_t)d * D + lane * 2;
        atomicAdd(ar,     xv.x * v);
        atomicAdd(ar + 1, xv.y * v);
    }
}

__global__ __launch_bounds__(256) void gemm_stats_kernel(
    const float* __restrict__ A,
    const float* __restrict__ W,
    float* __restrict__ h,
    float* __restrict__ stats,
    int n)
{
    __shared__ float sW[128 * 128];
    __shared__ float sA[32][128];
    const int tid = threadIdx.x;
    const float4* W4  = (const float4*)W;
    float4*       sW4 = (float4*)sW;
#pragma unroll
    for (int i = 0; i < 16; i++) sW4[tid + 256 * i] = W4[tid + 256 * i];
    const int row0 = blockIdx.x * 32;
    const float4* A4  = (const float4*)(A + (size_t)row0 * D);
    float4*       sA4 = (float4*)&sA[0][0];
#pragma unroll
    for (int i = 0; i < 4; i++) {
        int idx = tid + 256 * i;
        sA4[idx] = ((size_t)row0 * D + (size_t)idx * 4 < (size_t)n * D)
                       ? A4[idx] : make_float4(0.f, 0.f, 0.f, 0.f);
    }
    __syncthreads();
    const int tx = tid & 31, ty = tid >> 5, c0 = tx * 4;
    float acc[4][4] = {};
    for (int k = 0; k < 128; k++) {
        const float4 w = *(const float4*)&sW[k * 128 + c0];
#pragma unroll
        for (int j = 0; j < 4; j++) {
            const float a = sA[ty + 8 * j][k];
            acc[j][0] += a * w.x; acc[j][1] += a * w.y;
            acc[j][2] += a * w.z; acc[j][3] += a * w.w;
        }
    }
#pragma unroll
    for (int j = 0; j < 4; j++) {
        const int row = row0 + ty + 8 * j;
        if (row < n)
            *(float4*)&h[(size_t)row * D + c0] =
                make_float4(acc[j][0], acc[j][1], acc[j][2], acc[j][3]);
    }
    __syncthreads();
    float* csum = &sA[0][0];
    float* csq  = csum + 128;
    if (tid < 128) { csum[tid] = 0.f; csq[tid] = 0.f; }
    __syncthreads();
#pragma unroll
    for (int c = 0; c < 4; c++) {
        float s = 0.f, q = 0.f;
#pragma unroll
        for (int j = 0; j < 4; j++) { s += acc[j][c]; q += acc[j][c] * acc[j][c]; }
        atomicAdd(&csum[c0 + c], s);
        atomicAdd(&csq[c0 + c], q);
    }
    __syncthreads();
    if (tid < 128) {
        atomicAdd(&stats[tid],       csum[tid]);
        atomicAdd(&stats[128 + tid], csq[tid]);
    }
}

// ---------------------------------------------------------------------------
extern "C" void kernel_launch(void* const* d_in, const int* in_sizes, int n_in,
                              void* d_out, int out_size, void* d_ws, size_t ws_size,
                              hipStream_t stream)
{
    const float* x     = (const float*)d_in[0];
    const int*   esrc  = (const int*)d_in[1];
    const int*   edst  = (const int*)d_in[2];
    const float* evals = (const float*)d_in[3];
    const float* W     = (const float*)d_in[4];
    // d_in[5] = bias: unused — cancels exactly under BatchNorm.
    const float* gamma = (const float*)d_in[6];
    const float* beta  = (const float*)d_in[7];
    float* out = (float*)d_out;

    const int n = in_sizes[0] / D;   // 100000
    const int E = in_sizes[1];       // 1600000

    const int B    = (n + BROWS - 1) >> BSHIFT;   // 196 buckets
    const int nwgA = (E + TILE - 1) / TILE;       // 196 tiles

    // Workspace (word-indexed):
    //   yb          [n*64]          25.6 MB (packed bf16 y = x@W)
    //   bucket_cnt  [B]             zeroed
    //   stats       [256]           zeroed (adjacent -> one memset)
    //   bucket_base [B]
    //   ofs         [nwgA*(B+1)]    ~155 KB
    //   rowptr      [n]
    //   (pad to even word)
    //   slices      uint2[nwgA*TILE]  12.85 MB
    //   csr         ull  [E]          12.8 MB
    unsigned* yb         = (unsigned*)d_ws;
    int*      bucket_cnt = (int*)(yb + (size_t)n * 64);
    float*    stats      = (float*)(bucket_cnt + B);
    int*      bucket_base= (int*)(stats + 256);
    int*      ofs        = bucket_base + B;
    int*      rowptr     = ofs + (size_t)nwgA * (B + 1);
    size_t    w_off      = (size_t)n * 64 + B + 256 + B + (size_t)nwgA * (B + 1) + n;
    w_off += (w_off & 1);                         // 8B alignment
    uint2*    slices     = (uint2*)((unsigned*)d_ws + w_off);
    ull*      csr        = (ull*)(slices + (size_t)nwgA * TILE);
    const size_t need = (w_off + (size_t)nwgA * TILE * 2 + (size_t)E * 2) * 4;

    if (ws_size >= need && B <= 256) {
        hipMemsetAsync(bucket_cnt, 0, ((size_t)B + 256) * 4, stream);
        gemm_pack_kernel<<<(n + 31) / 32, 256, 0, stream>>>(x, W, yb, n);
        binA_kernel<<<nwgA, 256, 0, stream>>>(
            esrc, edst, evals, slices, ofs, bucket_cnt, B, E);
        bucket_scan_kernel<<<1, 256, 0, stream>>>(bucket_cnt, bucket_base, B);
        binB_kernel<<<B, 256, 0, stream>>>(
            slices, ofs, bucket_base, rowptr, csr, B, nwgA, n);
        spmm_csr_bf16_kernel<<<(n + 3) / 4, 256, 0, stream>>>(
            yb, rowptr, csr, out, n);
        stats_kernel<<<256, 256, 0, stream>>>(out, stats, n);
        bn_apply_kernel<<<2048, 256, 0, stream>>>(out, stats, gamma, beta, n);
    } else {
        // fallback: fp32 atomic-scatter path
        float* agg = (float*)d_ws;
        float* st  = agg + (size_t)n * D;
        hipMemsetAsync(d_ws, 0, ((size_t)n * D + 256) * 4, stream);
        spmm_atomic_kernel<<<4096, 256, 0, stream>>>(x, esrc, edst, evals, agg, E);
        gemm_stats_kernel<<<(n + 31) / 32, 256, 0, stream>>>(agg, W, out, st, n);
        bn_apply_kernel<<<2048, 256, 0, stream>>>(out, st, gamma, beta, n);
    }
}

// Round 6
// 378.974 us; speedup vs baseline: 1.3826x; 1.1064x over previous
//
#include <hip/hip_runtime.h>
#include <math.h>

// Problem constants: N=100000, E=1600000, D_IN=D_OUT=128
#define D 128
#define BSHIFT 9              // 512 dst rows per bucket
#define BROWS 512
#define TILE 8192             // edges per binA workgroup
constexpr float BN_EPS = 1e-5f;
typedef unsigned long long ull;

// bf16 helpers (manual, RNE) ------------------------------------------------
__device__ __forceinline__ unsigned f2bf_rne(float f) {
    unsigned u = __float_as_uint(f);
    return (u + 0x7FFFu + ((u >> 16) & 1u)) >> 16;
}
__device__ __forceinline__ float bf_lo(unsigned u) { return __uint_as_float(u << 16); }
__device__ __forceinline__ float bf_hi(unsigned u) { return __uint_as_float(u & 0xFFFF0000u); }

// ---------------------------------------------------------------------------
// GEMM y = x @ W, epilogue packs y to bf16 words (yb [n,64]).
// Associativity: h = (A x) W = A (x W) -> dense GEMM first, SpMM gathers y.
// ---------------------------------------------------------------------------
__global__ __launch_bounds__(256) void gemm_pack_kernel(
    const float* __restrict__ A,
    const float* __restrict__ W,
    unsigned* __restrict__ yb,
    int n)
{
    __shared__ float sW[128 * 128];
    __shared__ float sA[32][128];

    const int tid = threadIdx.x;

    const float4* W4  = (const float4*)W;
    float4*       sW4 = (float4*)sW;
#pragma unroll
    for (int i = 0; i < 16; i++) sW4[tid + 256 * i] = W4[tid + 256 * i];

    const int row0 = blockIdx.x * 32;
    const float4* A4  = (const float4*)(A + (size_t)row0 * D);
    float4*       sA4 = (float4*)&sA[0][0];
#pragma unroll
    for (int i = 0; i < 4; i++) {
        int idx = tid + 256 * i;
        sA4[idx] = ((size_t)row0 * D + (size_t)idx * 4 < (size_t)n * D)
                       ? A4[idx] : make_float4(0.f, 0.f, 0.f, 0.f);
    }
    __syncthreads();

    const int tx = tid & 31;
    const int ty = tid >> 5;
    const int c0 = tx * 4;

    float acc[4][4] = {};
    for (int k0 = 0; k0 < 128; k0 += 4) {
        float4 a[4];
#pragma unroll
        for (int j = 0; j < 4; j++)
            a[j] = *(const float4*)&sA[ty + 8 * j][k0];
#pragma unroll
        for (int kk = 0; kk < 4; kk++) {
            const float4 w = *(const float4*)&sW[(k0 + kk) * 128 + c0];
            const float ak[4] = { kk == 0 ? a[0].x : kk == 1 ? a[0].y : kk == 2 ? a[0].z : a[0].w,
                                  kk == 0 ? a[1].x : kk == 1 ? a[1].y : kk == 2 ? a[1].z : a[1].w,
                                  kk == 0 ? a[2].x : kk == 1 ? a[2].y : kk == 2 ? a[2].z : a[2].w,
                                  kk == 0 ? a[3].x : kk == 1 ? a[3].y : kk == 2 ? a[3].z : a[3].w };
#pragma unroll
            for (int j = 0; j < 4; j++) {
                acc[j][0] += ak[j] * w.x;
                acc[j][1] += ak[j] * w.y;
                acc[j][2] += ak[j] * w.z;
                acc[j][3] += ak[j] * w.w;
            }
        }
    }

#pragma unroll
    for (int j = 0; j < 4; j++) {
        const int row = row0 + ty + 8 * j;
        if (row < n) {
            uint2 o;
            o.x = f2bf_rne(acc[j][0]) | (f2bf_rne(acc[j][1]) << 16);
            o.y = f2bf_rne(acc[j][2]) | (f2bf_rne(acc[j][3]) << 16);
            ((uint2*)(yb + (size_t)row * 64))[tx] = o;
        }
    }
}

// ---------------------------------------------------------------------------
// binA: coarse bucket sort. Each wg owns edges [wg*TILE, ...) and a PRIVATE
// slice of the record buffer (block-private -> dense single-XCD writeback).
// Record: .x = dstLow(9b) | src<<9, .y = val bits.
// ofs table is TRANSPOSED: ofs_t[b * nwgA + wg] = run start of bucket b in
// slice wg; row B is the sentinel (tile edge count) so run end of bucket b
// is ofs_t[(b+1)*nwgA + wg].
// ---------------------------------------------------------------------------
__global__ __launch_bounds__(256) void binA_kernel(
    const int* __restrict__ esrc, const int* __restrict__ edst,
    const float* __restrict__ evals,
    uint2* __restrict__ slices,        // [nwgA * TILE]
    int* __restrict__ ofs_t,           // [(B+1) * nwgA]
    int* __restrict__ bucket_cnt,      // [B], pre-zeroed
    int B, int nwgA, int E)
{
    __shared__ int h[256];
    __shared__ int ps[256];
    __shared__ int cur[256];

    const int tid = threadIdx.x;
    const int wg  = blockIdx.x;
    const int e0  = wg * TILE;
    const int e1  = min(e0 + TILE, E);

    h[tid] = 0;
    __syncthreads();

    // phase 1: bucket histogram
    for (int e = e0 + tid; e < e1; e += 256)
        atomicAdd(&h[edst[e] >> BSHIFT], 1);
    __syncthreads();

    // phase 2: exclusive scan over B (<=256) buckets (Hillis-Steele)
    const int v = h[tid];
    ps[tid] = v;
    __syncthreads();
    for (int off = 1; off < 256; off <<= 1) {
        int t = (tid >= off) ? ps[tid - off] : 0;
        __syncthreads();
        if (tid >= off) ps[tid] += t;
        __syncthreads();
    }
    const int excl = ps[tid] - v;
    if (tid < B) {
        cur[tid] = excl;
        ofs_t[(size_t)tid * nwgA + wg] = excl;
        if (v) atomicAdd(&bucket_cnt[tid], v);
    }
    if (tid == 0) ofs_t[(size_t)B * nwgA + wg] = e1 - e0;   // sentinel row
    __syncthreads();

    // phase 3: place records into private slice (edst re-read is L2-hot)
    uint2* slice = slices + (size_t)wg * TILE;
    for (int e = e0 + tid; e < e1; e += 256) {
        int d = edst[e];
        int b = d >> BSHIFT;
        int p = atomicAdd(&cur[b], 1);
        uint2 rec;
        rec.x = (unsigned)(d & (BROWS - 1)) | ((unsigned)esrc[e] << BSHIFT);
        rec.y = __float_as_uint(evals[e]);
        slice[p] = rec;
    }
}

// ---------------------------------------------------------------------------
// binB: one 1024-thread wg (16 waves) per bucket.
//  - loads its two ofs_t rows (run bounds across all nwgA slices) into LDS
//  - computes bucket base by reducing bucket_cnt[0..b) in LDS (replaces the
//    separate bucket_scan kernel)
//  - pass 1: row histogram over this bucket's runs
//  - 512-row LDS scan -> global end-form rowptr + LDS cursors
//  - pass 2: scatter records into the bucket-private csr window (L2-hot
//    re-read: ~65KB/bucket, ~1.6MB concurrent per XCD < 4MB L2)
// 16 waves/CU vs round-5's 4 -> 4x fewer sequential run-chains per wave.
// ---------------------------------------------------------------------------
__global__ __launch_bounds__(1024) void binB_kernel(
    const uint2* __restrict__ slices,
    const int* __restrict__ ofs_t,
    const int* __restrict__ bucket_cnt,
    int* __restrict__ rowptr,          // [n], end-form
    ull* __restrict__ csr,             // [E]
    int B, int nwgA, int n)
{
    __shared__ int srow[256];
    __shared__ int erow[256];
    __shared__ int red[256];
    __shared__ int hist[BROWS];
    __shared__ int curs[BROWS];
    __shared__ int ps[BROWS];
    __shared__ int s_bbase;

    const int tid  = threadIdx.x;
    const int b    = blockIdx.x;
    const int w    = tid >> 6;
    const int lane = tid & 63;

    // stage run bounds (coalesced: two contiguous rows of nwgA ints)
    for (int i = tid; i < nwgA; i += 1024) {
        srow[i] = ofs_t[(size_t)b * nwgA + i];
        erow[i] = ofs_t[(size_t)(b + 1) * nwgA + i];
    }
    if (tid < BROWS) hist[tid] = 0;
    // bucket base = sum of bucket_cnt[0..b)
    if (tid < 256) red[tid] = (tid < b) ? bucket_cnt[tid] : 0;
    __syncthreads();
    for (int off = 128; off > 0; off >>= 1) {
        if (tid < off) red[tid] += red[tid + off];
        __syncthreads();
    }
    if (tid == 0) s_bbase = red[0];
    __syncthreads();

    // pass 1: in-bucket row histogram
    for (int wg = w; wg < nwgA; wg += 16) {
        const int s = srow[wg];
        const int e = erow[wg];
        const uint2* run = slices + (size_t)wg * TILE;
        for (int i = s + lane; i < e; i += 64)
            atomicAdd(&hist[run[i].x & (BROWS - 1)], 1);
    }
    __syncthreads();

    // 512-row exclusive scan (Hillis-Steele, tid<512 active, uniform barriers)
    int v0 = 0;
    if (tid < BROWS) { v0 = hist[tid]; ps[tid] = v0; }
    __syncthreads();
    for (int off = 1; off < BROWS; off <<= 1) {
        int t = 0;
        if (tid < BROWS && tid >= off) t = ps[tid - off];
        __syncthreads();
        if (tid < BROWS) ps[tid] += t;
        __syncthreads();
    }
    if (tid < BROWS) {
        const int excl = s_bbase + ps[tid] - v0;
        curs[tid] = excl;                       // row start
        const int r = (b << BSHIFT) + tid;
        if (r < n) rowptr[r] = excl + v0;       // row end
    }
    __syncthreads();

    // pass 2: scatter into final CSR positions (bucket-private window)
    for (int wg = w; wg < nwgA; wg += 16) {
        const int s = srow[wg];
        const int e = erow[wg];
        const uint2* run = slices + (size_t)wg * TILE;
        for (int i = s + lane; i < e; i += 64) {
            uint2 r = run[i];
            int pos = atomicAdd(&curs[r.x & (BROWS - 1)], 1);
            csr[pos] = ((ull)r.y << 32) | (r.x >> BSHIFT);
        }
    }
}

// ---------------------------------------------------------------------------
// CSR SpMM: h[dst] = sum val * y[src]  (bf16 y gather, fp32 accumulate).
// One wave per dst row; lane handles 2 cols. 4-edge unroll. Output -> d_out.
// ---------------------------------------------------------------------------
__global__ __launch_bounds__(256) void spmm_csr_bf16_kernel(
    const unsigned* __restrict__ yb,
    const int* __restrict__ rowptr,   // end-form
    const ull* __restrict__ csr,
    float* __restrict__ h, int n)
{
    int wave = (blockIdx.x * blockDim.x + threadIdx.x) >> 6;
    int lane = threadIdx.x & 63;
    if (wave >= n) return;
    int start = (wave == 0) ? 0 : rowptr[wave - 1];
    int end   = rowptr[wave];

    float ax = 0.f, ay = 0.f;
    int e = start;
    for (; e + 3 < end; e += 4) {
        ull e0 = csr[e], e1 = csr[e + 1], e2 = csr[e + 2], e3 = csr[e + 3];
        unsigned u0 = yb[(size_t)(unsigned)e0 * 64 + lane];
        unsigned u1 = yb[(size_t)(unsigned)e1 * 64 + lane];
        unsigned u2 = yb[(size_t)(unsigned)e2 * 64 + lane];
        unsigned u3 = yb[(size_t)(unsigned)e3 * 64 + lane];
        float v0 = __uint_as_float((unsigned)(e0 >> 32));
        float v1 = __uint_as_float((unsigned)(e1 >> 32));
        float v2 = __uint_as_float((unsigned)(e2 >> 32));
        float v3 = __uint_as_float((unsigned)(e3 >> 32));
        ax += v0 * bf_lo(u0) + v1 * bf_lo(u1) + v2 * bf_lo(u2) + v3 * bf_lo(u3);
        ay += v0 * bf_hi(u0) + v1 * bf_hi(u1) + v2 * bf_hi(u2) + v3 * bf_hi(u3);
    }
    for (; e < end; e++) {
        ull ed = csr[e];
        unsigned u = yb[(size_t)(unsigned)ed * 64 + lane];
        float v = __uint_as_float((unsigned)(ed >> 32));
        ax += v * bf_lo(u);
        ay += v * bf_hi(u);
    }
    ((float2*)(h + (size_t)wave * D))[lane] = make_float2(ax, ay);
}

// ---------------------------------------------------------------------------
// Column stats of h.
// ---------------------------------------------------------------------------
__global__ __launch_bounds__(256) void stats_kernel(
    const float* __restrict__ h,
    float* __restrict__ stats,   // [0..127]=sum, [128..255]=sumsq
    int n)
{
    __shared__ float ssum[256];
    __shared__ float ssq[256];
    const int tid  = threadIdx.x;
    const int col  = tid & 127;
    const int half = tid >> 7;

    float s = 0.f, q = 0.f;
    for (int r = blockIdx.x * 2 + half; r < n; r += gridDim.x * 2) {
        const float v = h[(size_t)r * D + col];
        s += v;
        q += v * v;
    }
    ssum[tid] = s;
    ssq[tid]  = q;
    __syncthreads();
    if (tid < 128) {
        atomicAdd(&stats[col],       ssum[tid] + ssum[tid + 128]);
        atomicAdd(&stats[128 + col], ssq[tid] + ssq[tid + 128]);
    }
}

// ---------------------------------------------------------------------------
// In-place BatchNorm apply. Linear bias cancels under BN -> omitted.
// ---------------------------------------------------------------------------
__global__ __launch_bounds__(256) void bn_apply_kernel(
    float* __restrict__ h,
    const float* __restrict__ stats,
    const float* __restrict__ gamma,
    const float* __restrict__ beta,
    int n)
{
    __shared__ float s_scale[128];
    __shared__ float s_shift[128];
    const int tid = threadIdx.x;
    if (tid < 128) {
        const float invn = 1.0f / (float)n;
        const float mean = stats[tid] * invn;
        const float var  = stats[128 + tid] * invn - mean * mean;
        const float inv  = rsqrtf(var + BN_EPS);
        const float g    = gamma[tid] * inv;
        s_scale[tid] = g;
        s_shift[tid] = beta[tid] - mean * g;
    }
    __syncthreads();

    float4* h4 = (float4*)h;
    const size_t total = (size_t)n * D / 4;
    const size_t stride = (size_t)gridDim.x * blockDim.x;
    for (size_t i = (size_t)blockIdx.x * blockDim.x + tid; i < total; i += stride) {
        float4 v = h4[i];
        const int c = (int)((i * 4) & (D - 1));
        v.x = v.x * s_scale[c]     + s_shift[c];
        v.y = v.y * s_scale[c + 1] + s_shift[c + 1];
        v.z = v.z * s_scale[c + 2] + s_shift[c + 2];
        v.w = v.w * s_scale[c + 3] + s_shift[c + 3];
        h4[i] = v;
    }
}

// ---------------------------------------------------------------------------
// Fallback (ws too small / shape mismatch): atomic SpMM + GEMM w/ stats.
// ---------------------------------------------------------------------------
__global__ __launch_bounds__(256) void spmm_atomic_kernel(
    const float* __restrict__ x,
    const int* __restrict__ esrc, const int* __restrict__ edst,
    const float* __restrict__ eval, float* __restrict__ agg, int E)
{
    int wave  = (blockIdx.x * blockDim.x + threadIdx.x) >> 6;
    int lane  = threadIdx.x & 63;
    int nwave = (gridDim.x * blockDim.x) >> 6;
    for (int e = wave; e < E; e += nwave) {
        int   s = esrc[e];
        int   d = edst[e];
        float v = eval[e];
        const float2 xv = ((const float2*)(x + (size_t)s * D))[lane];
        float* ar = agg + (size_t)d * D + lane * 2;
        atomicAdd(ar,     xv.x * v);
        atomicAdd(ar + 1, xv.y * v);
    }
}

__global__ __launch_bounds__(256) void gemm_stats_kernel(
    const float* __restrict__ A,
    const float* __restrict__ W,
    float* __restrict__ h,
    float* __restrict__ stats,
    int n)
{
    __shared__ float sW[128 * 128];
    __shared__ float sA[32][128];
    const int tid = threadIdx.x;
    const float4* W4  = (const float4*)W;
    float4*       sW4 = (float4*)sW;
#pragma unroll
    for (int i = 0; i < 16; i++) sW4[tid + 256 * i] = W4[tid + 256 * i];
    const int row0 = blockIdx.x * 32;
    const float4* A4  = (const float4*)(A + (size_t)row0 * D);
    float4*       sA4 = (float4*)&sA[0][0];
#pragma unroll
    for (int i = 0; i < 4; i++) {
        int idx = tid + 256 * i;
        sA4[idx] = ((size_t)row0 * D + (size_t)idx * 4 < (size_t)n * D)
                       ? A4[idx] : make_float4(0.f, 0.f, 0.f, 0.f);
    }
    __syncthreads();
    const int tx = tid & 31, ty = tid >> 5, c0 = tx * 4;
    float acc[4][4] = {};
    for (int k = 0; k < 128; k++) {
        const float4 w = *(const float4*)&sW[k * 128 + c0];
#pragma unroll
        for (int j = 0; j < 4; j++) {
            const float a = sA[ty + 8 * j][k];
            acc[j][0] += a * w.x; acc[j][1] += a * w.y;
            acc[j][2] += a * w.z; acc[j][3] += a * w.w;
        }
    }
#pragma unroll
    for (int j = 0; j < 4; j++) {
        const int row = row0 + ty + 8 * j;
        if (row < n)
            *(float4*)&h[(size_t)row * D + c0] =
                make_float4(acc[j][0], acc[j][1], acc[j][2], acc[j][3]);
    }
    __syncthreads();
    float* csum = &sA[0][0];
    float* csq  = csum + 128;
    if (tid < 128) { csum[tid] = 0.f; csq[tid] = 0.f; }
    __syncthreads();
#pragma unroll
    for (int c = 0; c < 4; c++) {
        float s = 0.f, q = 0.f;
#pragma unroll
        for (int j = 0; j < 4; j++) { s += acc[j][c]; q += acc[j][c] * acc[j][c]; }
        atomicAdd(&csum[c0 + c], s);
        atomicAdd(&csq[c0 + c], q);
    }
    __syncthreads();
    if (tid < 128) {
        atomicAdd(&stats[tid],       csum[tid]);
        atomicAdd(&stats[128 + tid], csq[tid]);
    }
}

// ---------------------------------------------------------------------------
extern "C" void kernel_launch(void* const* d_in, const int* in_sizes, int n_in,
                              void* d_out, int out_size, void* d_ws, size_t ws_size,
                              hipStream_t stream)
{
    const float* x     = (const float*)d_in[0];
    const int*   esrc  = (const int*)d_in[1];
    const int*   edst  = (const int*)d_in[2];
    const float* evals = (const float*)d_in[3];
    const float* W     = (const float*)d_in[4];
    // d_in[5] = bias: unused — cancels exactly under BatchNorm.
    const float* gamma = (const float*)d_in[6];
    const float* beta  = (const float*)d_in[7];
    float* out = (float*)d_out;

    const int n = in_sizes[0] / D;   // 100000
    const int E = in_sizes[1];       // 1600000

    const int B    = (n + BROWS - 1) >> BSHIFT;   // 196 buckets
    const int nwgA = (E + TILE - 1) / TILE;       // 196 tiles

    // Workspace (word-indexed):
    //   yb          [n*64]            25.6 MB (packed bf16 y = x@W)
    //   bucket_cnt  [B]               zeroed
    //   stats       [256]             zeroed (adjacent -> one memset)
    //   ofs_t       [(B+1)*nwgA]      ~155 KB (transposed: [bucket][wg])
    //   rowptr      [n]
    //   (pad to even word)
    //   slices      uint2[nwgA*TILE]  12.85 MB
    //   csr         ull  [E]          12.8 MB
    unsigned* yb         = (unsigned*)d_ws;
    int*      bucket_cnt = (int*)(yb + (size_t)n * 64);
    float*    stats      = (float*)(bucket_cnt + B);
    int*      ofs_t      = (int*)(stats + 256);
    int*      rowptr     = ofs_t + (size_t)(B + 1) * nwgA;
    size_t    w_off      = (size_t)n * 64 + B + 256 + (size_t)(B + 1) * nwgA + n;
    w_off += (w_off & 1);                         // 8B alignment
    uint2*    slices     = (uint2*)((unsigned*)d_ws + w_off);
    ull*      csr        = (ull*)(slices + (size_t)nwgA * TILE);
    const size_t need = (w_off + (size_t)nwgA * TILE * 2 + (size_t)E * 2) * 4;

    if (ws_size >= need && B <= 256 && nwgA <= 256) {
        hipMemsetAsync(bucket_cnt, 0, ((size_t)B + 256) * 4, stream);
        gemm_pack_kernel<<<(n + 31) / 32, 256, 0, stream>>>(x, W, yb, n);
        binA_kernel<<<nwgA, 256, 0, stream>>>(
            esrc, edst, evals, slices, ofs_t, bucket_cnt, B, nwgA, E);
        binB_kernel<<<B, 1024, 0, stream>>>(
            slices, ofs_t, bucket_cnt, rowptr, csr, B, nwgA, n);
        spmm_csr_bf16_kernel<<<(n + 3) / 4, 256, 0, stream>>>(
            yb, rowptr, csr, out, n);
        stats_kernel<<<256, 256, 0, stream>>>(out, stats, n);
        bn_apply_kernel<<<2048, 256, 0, stream>>>(out, stats, gamma, beta, n);
    } else {
        // fallback: fp32 atomic-scatter path
        float* agg = (float*)d_ws;
        float* st  = agg + (size_t)n * D;
        hipMemsetAsync(d_ws, 0, ((size_t)n * D + 256) * 4, stream);
        spmm_atomic_kernel<<<4096, 256, 0, stream>>>(x, esrc, edst, evals, agg, E);
        gemm_stats_kernel<<<(n + 31) / 32, 256, 0, stream>>>(agg, W, out, st, n);
        bn_apply_kernel<<<2048, 256, 0, stream>>>(out, st, gamma, beta, n);
    }
}

// Round 7
// 314.026 us; speedup vs baseline: 1.6686x; 1.2068x over previous
//
#include <hip/hip_runtime.h>
#include <math.h>

// Problem constants: N=100000, E=1600000, D_IN=D_OUT=128
#define D 128
#define BSHIFT 9              // 512 dst rows per bucket
#define BROWS 512
#define TILE 8192             // edges per binA workgroup
constexpr float BN_EPS = 1e-5f;
typedef unsigned long long ull;

// bf16 helpers (manual, RNE) ------------------------------------------------
__device__ __forceinline__ unsigned f2bf_rne(float f) {
    unsigned u = __float_as_uint(f);
    return (u + 0x7FFFu + ((u >> 16) & 1u)) >> 16;
}
__device__ __forceinline__ float bf_lo(unsigned u) { return __uint_as_float(u << 16); }
__device__ __forceinline__ float bf_hi(unsigned u) { return __uint_as_float(u & 0xFFFF0000u); }

// ---------------------------------------------------------------------------
// phase1: fused dispatch. Blocks [0,nwgA) run binA (bucket sort pass A);
// blocks [nwgA, nwgA+ngemm) run gemm_pack (y = x@W, packed to bf16).
// Disjoint inputs -> they overlap; critical path = max, not sum.
// binA's 3KB of LDS is aliased into gemm's 80KB buffer so the LDS footprint
// stays 80KB -> 2 blocks/CU either way.
// ---------------------------------------------------------------------------
__global__ __launch_bounds__(256) void phase1_kernel(
    const float* __restrict__ A,
    const float* __restrict__ W,
    unsigned* __restrict__ yb,
    int n,
    const int* __restrict__ esrc, const int* __restrict__ edst,
    const float* __restrict__ evals,
    uint2* __restrict__ slices,        // [nwgA * TILE]
    int* __restrict__ ofs_t,           // [(B+1) * nwgA], transposed [bucket][wg]
    int B, int nwgA, int E)
{
    __shared__ __align__(16) char smem[81920];
    const int tid = threadIdx.x;

    if ((int)blockIdx.x < nwgA) {
        // ------------------- binA: coarse bucket sort -------------------
        // Each wg owns a PRIVATE slice (block-private -> dense single-XCD
        // writeback; round-5 counters confirmed WRITE ~= payload).
        int* h   = (int*)smem;
        int* ps  = h + 256;
        int* cur = ps + 256;
        const int wg = blockIdx.x;
        const int e0 = wg * TILE;
        const int e1 = min(e0 + TILE, E);

        h[tid] = 0;
        __syncthreads();
        for (int e = e0 + tid; e < e1; e += 256)
            atomicAdd(&h[edst[e] >> BSHIFT], 1);
        __syncthreads();

        const int v = h[tid];
        ps[tid] = v;
        __syncthreads();
        for (int off = 1; off < 256; off <<= 1) {
            int t = (tid >= off) ? ps[tid - off] : 0;
            __syncthreads();
            if (tid >= off) ps[tid] += t;
            __syncthreads();
        }
        const int excl = ps[tid] - v;
        if (tid < B) {
            cur[tid] = excl;
            ofs_t[(size_t)tid * nwgA + wg] = excl;
        }
        if (tid == 0) ofs_t[(size_t)B * nwgA + wg] = e1 - e0;  // sentinel
        __syncthreads();

        uint2* slice = slices + (size_t)wg * TILE;
        for (int e = e0 + tid; e < e1; e += 256) {
            int d = edst[e];
            int b = d >> BSHIFT;
            int p = atomicAdd(&cur[b], 1);
            uint2 rec;
            rec.x = (unsigned)(d & (BROWS - 1)) | ((unsigned)esrc[e] << BSHIFT);
            rec.y = __float_as_uint(evals[e]);
            slice[p] = rec;
        }
    } else {
        // ------------------- gemm_pack: y = x@W -> bf16 -------------------
        float* sW = (float*)smem;                          // 64 KB
        float (*sA)[128] = (float(*)[128])(smem + 65536);  // 16 KB

        const float4* W4  = (const float4*)W;
        float4*       sW4 = (float4*)sW;
#pragma unroll
        for (int i = 0; i < 16; i++) sW4[tid + 256 * i] = W4[tid + 256 * i];

        const int row0 = (blockIdx.x - nwgA) * 32;
        const float4* A4  = (const float4*)(A + (size_t)row0 * D);
        float4*       sA4 = (float4*)&sA[0][0];
#pragma unroll
        for (int i = 0; i < 4; i++) {
            int idx = tid + 256 * i;
            sA4[idx] = ((size_t)row0 * D + (size_t)idx * 4 < (size_t)n * D)
                           ? A4[idx] : make_float4(0.f, 0.f, 0.f, 0.f);
        }
        __syncthreads();

        const int tx = tid & 31;
        const int ty = tid >> 5;
        const int c0 = tx * 4;

        float acc[4][4] = {};
        for (int k0 = 0; k0 < 128; k0 += 4) {
            float4 a[4];
#pragma unroll
            for (int j = 0; j < 4; j++)
                a[j] = *(const float4*)&sA[ty + 8 * j][k0];
#pragma unroll
            for (int kk = 0; kk < 4; kk++) {
                const float4 w = *(const float4*)&sW[(k0 + kk) * 128 + c0];
                const float ak[4] = { kk == 0 ? a[0].x : kk == 1 ? a[0].y : kk == 2 ? a[0].z : a[0].w,
                                      kk == 0 ? a[1].x : kk == 1 ? a[1].y : kk == 2 ? a[1].z : a[1].w,
                                      kk == 0 ? a[2].x : kk == 1 ? a[2].y : kk == 2 ? a[2].z : a[2].w,
                                      kk == 0 ? a[3].x : kk == 1 ? a[3].y : kk == 2 ? a[3].z : a[3].w };
#pragma unroll
                for (int j = 0; j < 4; j++) {
                    acc[j][0] += ak[j] * w.x;
                    acc[j][1] += ak[j] * w.y;
                    acc[j][2] += ak[j] * w.z;
                    acc[j][3] += ak[j] * w.w;
                }
            }
        }

#pragma unroll
        for (int j = 0; j < 4; j++) {
            const int row = row0 + ty + 8 * j;
            if (row < n) {
                uint2 o;
                o.x = f2bf_rne(acc[j][0]) | (f2bf_rne(acc[j][1]) << 16);
                o.y = f2bf_rne(acc[j][2]) | (f2bf_rne(acc[j][3]) << 16);
                ((uint2*)(yb + (size_t)row * 64))[tx] = o;
            }
        }
    }
}

// ---------------------------------------------------------------------------
// binB: one 1024-thread wg (16 waves) per bucket.
// Bucket base = sum over wg of ofs_t[b][wg] (= #edges in buckets < b within
// each slice) -- no separate bucket_cnt array or scan kernel needed.
// ---------------------------------------------------------------------------
__global__ __launch_bounds__(1024) void binB_kernel(
    const uint2* __restrict__ slices,
    const int* __restrict__ ofs_t,
    int* __restrict__ rowptr,          // [n], end-form
    ull* __restrict__ csr,             // [E]
    int B, int nwgA, int n)
{
    __shared__ int srow[256];
    __shared__ int erow[256];
    __shared__ int red[256];
    __shared__ int hist[BROWS];
    __shared__ int curs[BROWS];
    __shared__ int ps[BROWS];
    __shared__ int s_bbase;

    const int tid  = threadIdx.x;
    const int b    = blockIdx.x;
    const int w    = tid >> 6;
    const int lane = tid & 63;

    // stage run bounds (coalesced: two contiguous rows of nwgA ints)
    for (int i = tid; i < nwgA; i += 1024) {
        srow[i] = ofs_t[(size_t)b * nwgA + i];
        erow[i] = ofs_t[(size_t)(b + 1) * nwgA + i];
    }
    if (tid < BROWS) hist[tid] = 0;
    __syncthreads();

    // bucket base = sum(srow[0..nwgA))
    if (tid < 256) red[tid] = (tid < nwgA) ? srow[tid] : 0;
    __syncthreads();
    for (int off = 128; off > 0; off >>= 1) {
        if (tid < off) red[tid] += red[tid + off];
        __syncthreads();
    }
    if (tid == 0) s_bbase = red[0];
    __syncthreads();

    // pass 1: in-bucket row histogram
    for (int wg = w; wg < nwgA; wg += 16) {
        const int s = srow[wg];
        const int e = erow[wg];
        const uint2* run = slices + (size_t)wg * TILE;
        for (int i = s + lane; i < e; i += 64)
            atomicAdd(&hist[run[i].x & (BROWS - 1)], 1);
    }
    __syncthreads();

    // 512-row exclusive scan (Hillis-Steele, tid<512 active, uniform barriers)
    int v0 = 0;
    if (tid < BROWS) { v0 = hist[tid]; ps[tid] = v0; }
    __syncthreads();
    for (int off = 1; off < BROWS; off <<= 1) {
        int t = 0;
        if (tid < BROWS && tid >= off) t = ps[tid - off];
        __syncthreads();
        if (tid < BROWS) ps[tid] += t;
        __syncthreads();
    }
    if (tid < BROWS) {
        const int excl = s_bbase + ps[tid] - v0;
        curs[tid] = excl;                       // row start
        const int r = (b << BSHIFT) + tid;
        if (r < n) rowptr[r] = excl + v0;       // row end
    }
    __syncthreads();

    // pass 2: scatter into final CSR positions (bucket-private window)
    for (int wg = w; wg < nwgA; wg += 16) {
        const int s = srow[wg];
        const int e = erow[wg];
        const uint2* run = slices + (size_t)wg * TILE;
        for (int i = s + lane; i < e; i += 64) {
            uint2 r = run[i];
            int pos = atomicAdd(&curs[r.x & (BROWS - 1)], 1);
            csr[pos] = ((ull)r.y << 32) | (r.x >> BSHIFT);
        }
    }
}

// ---------------------------------------------------------------------------
// CSR SpMM + fused column stats.
// 16 rows per wave (64 rows/block, 1563 blocks): per-lane register running
// sum/sumsq across the wave's rows, LDS reduce, one 256-atomic epilogue per
// block (~400k global stat atomics total ~= 10us).
// 8-edge unroll doubles outstanding gathers vs round-6 (was latency-bound:
// 36% VALUBusy, 16 VGPR).
// ---------------------------------------------------------------------------
__global__ __launch_bounds__(256) void spmm_stats_kernel(
    const unsigned* __restrict__ yb,
    const int* __restrict__ rowptr,   // end-form
    const ull* __restrict__ csr,
    float* __restrict__ h,
    float* __restrict__ stats,        // [0..127]=sum, [128..255]=sumsq, zeroed
    int n)
{
    __shared__ float ssum[128];
    __shared__ float ssq[128];
    const int tid  = threadIdx.x;
    const int wv   = tid >> 6;
    const int lane = tid & 63;
    const int rbase = blockIdx.x * 64 + wv * 16;

    if (tid < 128) { ssum[tid] = 0.f; ssq[tid] = 0.f; }
    __syncthreads();

    float sx = 0.f, sy = 0.f, qx = 0.f, qy = 0.f;
    for (int i = 0; i < 16; i++) {
        const int r = rbase + i;
        if (r >= n) break;
        const int start = r ? rowptr[r - 1] : 0;
        const int end   = rowptr[r];

        float ax = 0.f, ay = 0.f;
        int e = start;
        for (; e + 7 < end; e += 8) {
            ull e0 = csr[e],     e1 = csr[e + 1], e2 = csr[e + 2], e3 = csr[e + 3];
            ull e4 = csr[e + 4], e5 = csr[e + 5], e6 = csr[e + 6], e7 = csr[e + 7];
            unsigned u0 = yb[(size_t)(unsigned)e0 * 64 + lane];
            unsigned u1 = yb[(size_t)(unsigned)e1 * 64 + lane];
            unsigned u2 = yb[(size_t)(unsigned)e2 * 64 + lane];
            unsigned u3 = yb[(size_t)(unsigned)e3 * 64 + lane];
            unsigned u4 = yb[(size_t)(unsigned)e4 * 64 + lane];
            unsigned u5 = yb[(size_t)(unsigned)e5 * 64 + lane];
            unsigned u6 = yb[(size_t)(unsigned)e6 * 64 + lane];
            unsigned u7 = yb[(size_t)(unsigned)e7 * 64 + lane];
            float v0 = __uint_as_float((unsigned)(e0 >> 32));
            float v1 = __uint_as_float((unsigned)(e1 >> 32));
            float v2 = __uint_as_float((unsigned)(e2 >> 32));
            float v3 = __uint_as_float((unsigned)(e3 >> 32));
            float v4 = __uint_as_float((unsigned)(e4 >> 32));
            float v5 = __uint_as_float((unsigned)(e5 >> 32));
            float v6 = __uint_as_float((unsigned)(e6 >> 32));
            float v7 = __uint_as_float((unsigned)(e7 >> 32));
            ax += v0 * bf_lo(u0) + v1 * bf_lo(u1) + v2 * bf_lo(u2) + v3 * bf_lo(u3)
                + v4 * bf_lo(u4) + v5 * bf_lo(u5) + v6 * bf_lo(u6) + v7 * bf_lo(u7);
            ay += v0 * bf_hi(u0) + v1 * bf_hi(u1) + v2 * bf_hi(u2) + v3 * bf_hi(u3)
                + v4 * bf_hi(u4) + v5 * bf_hi(u5) + v6 * bf_hi(u6) + v7 * bf_hi(u7);
        }
        for (; e + 3 < end; e += 4) {
            ull e0 = csr[e], e1 = csr[e + 1], e2 = csr[e + 2], e3 = csr[e + 3];
            unsigned u0 = yb[(size_t)(unsigned)e0 * 64 + lane];
            unsigned u1 = yb[(size_t)(unsigned)e1 * 64 + lane];
            unsigned u2 = yb[(size_t)(unsigned)e2 * 64 + lane];
            unsigned u3 = yb[(size_t)(unsigned)e3 * 64 + lane];
            float v0 = __uint_as_float((unsigned)(e0 >> 32));
            float v1 = __uint_as_float((unsigned)(e1 >> 32));
            float v2 = __uint_as_float((unsigned)(e2 >> 32));
            float v3 = __uint_as_float((unsigned)(e3 >> 32));
            ax += v0 * bf_lo(u0) + v1 * bf_lo(u1) + v2 * bf_lo(u2) + v3 * bf_lo(u3);
            ay += v0 * bf_hi(u0) + v1 * bf_hi(u1) + v2 * bf_hi(u2) + v3 * bf_hi(u3);
        }
        for (; e < end; e++) {
            ull ed = csr[e];
            unsigned u = yb[(size_t)(unsigned)ed * 64 + lane];
            float v = __uint_as_float((unsigned)(ed >> 32));
            ax += v * bf_lo(u);
            ay += v * bf_hi(u);
        }
        ((float2*)(h + (size_t)r * D))[lane] = make_float2(ax, ay);
        sx += ax; sy += ay; qx += ax * ax; qy += ay * ay;
    }

    atomicAdd(&ssum[2 * lane],     sx);
    atomicAdd(&ssum[2 * lane + 1], sy);
    atomicAdd(&ssq[2 * lane],      qx);
    atomicAdd(&ssq[2 * lane + 1],  qy);
    __syncthreads();
    if (tid < 128) {
        atomicAdd(&stats[tid],       ssum[tid]);
        atomicAdd(&stats[128 + tid], ssq[tid]);
    }
}

// ---------------------------------------------------------------------------
// In-place BatchNorm apply. Linear bias cancels under BN -> omitted.
// ---------------------------------------------------------------------------
__global__ __launch_bounds__(256) void bn_apply_kernel(
    float* __restrict__ h,
    const float* __restrict__ stats,
    const float* __restrict__ gamma,
    const float* __restrict__ beta,
    int n)
{
    __shared__ float s_scale[128];
    __shared__ float s_shift[128];
    const int tid = threadIdx.x;
    if (tid < 128) {
        const float invn = 1.0f / (float)n;
        const float mean = stats[tid] * invn;
        const float var  = stats[128 + tid] * invn - mean * mean;
        const float inv  = rsqrtf(var + BN_EPS);
        const float g    = gamma[tid] * inv;
        s_scale[tid] = g;
        s_shift[tid] = beta[tid] - mean * g;
    }
    __syncthreads();

    float4* h4 = (float4*)h;
    const size_t total = (size_t)n * D / 4;
    const size_t stride = (size_t)gridDim.x * blockDim.x;
    for (size_t i = (size_t)blockIdx.x * blockDim.x + tid; i < total; i += stride) {
        float4 v = h4[i];
        const int c = (int)((i * 4) & (D - 1));
        v.x = v.x * s_scale[c]     + s_shift[c];
        v.y = v.y * s_scale[c + 1] + s_shift[c + 1];
        v.z = v.z * s_scale[c + 2] + s_shift[c + 2];
        v.w = v.w * s_scale[c + 3] + s_shift[c + 3];
        h4[i] = v;
    }
}

// ---------------------------------------------------------------------------
// Fallback (ws too small / shape mismatch): atomic SpMM + GEMM w/ stats.
// ---------------------------------------------------------------------------
__global__ __launch_bounds__(256) void spmm_atomic_kernel(
    const float* __restrict__ x,
    const int* __restrict__ esrc, const int* __restrict__ edst,
    const float* __restrict__ eval, float* __restrict__ agg, int E)
{
    int wave  = (blockIdx.x * blockDim.x + threadIdx.x) >> 6;
    int lane  = threadIdx.x & 63;
    int nwave = (gridDim.x * blockDim.x) >> 6;
    for (int e = wave; e < E; e += nwave) {
        int   s = esrc[e];
        int   d = edst[e];
        float v = eval[e];
        const float2 xv = ((const float2*)(x + (size_t)s * D))[lane];
        float* ar = agg + (size_t)d * D + lane * 2;
        atomicAdd(ar,     xv.x * v);
        atomicAdd(ar + 1, xv.y * v);
    }
}

__global__ __launch_bounds__(256) void gemm_stats_kernel(
    const float* __restrict__ A,
    const float* __restrict__ W,
    float* __restrict__ h,
    float* __restrict__ stats,
    int n)
{
    __shared__ float sW[128 * 128];
    __shared__ float sA[32][128];
    const int tid = threadIdx.x;
    const float4* W4  = (const float4*)W;
    float4*       sW4 = (float4*)sW;
#pragma unroll
    for (int i = 0; i < 16; i++) sW4[tid + 256 * i] = W4[tid + 256 * i];
    const int row0 = blockIdx.x * 32;
    const float4* A4  = (const float4*)(A + (size_t)row0 * D);
    float4*       sA4 = (float4*)&sA[0][0];
#pragma unroll
    for (int i = 0; i < 4; i++) {
        int idx = tid + 256 * i;
        sA4[idx] = ((size_t)row0 * D + (size_t)idx * 4 < (size_t)n * D)
                       ? A4[idx] : make_float4(0.f, 0.f, 0.f, 0.f);
    }
    __syncthreads();
    const int tx = tid & 31, ty = tid >> 5, c0 = tx * 4;
    float acc[4][4] = {};
    for (int k = 0; k < 128; k++) {
        const float4 w = *(const float4*)&sW[k * 128 + c0];
#pragma unroll
        for (int j = 0; j < 4; j++) {
            const float a = sA[ty + 8 * j][k];
            acc[j][0] += a * w.x; acc[j][1] += a * w.y;
            acc[j][2] += a * w.z; acc[j][3] += a * w.w;
        }
    }
#pragma unroll
    for (int j = 0; j < 4; j++) {
        const int row = row0 + ty + 8 * j;
        if (row < n)
            *(float4*)&h[(size_t)row * D + c0] =
                make_float4(acc[j][0], acc[j][1], acc[j][2], acc[j][3]);
    }
    __syncthreads();
    float* csum = &sA[0][0];
    float* csq  = csum + 128;
    if (tid < 128) { csum[tid] = 0.f; csq[tid] = 0.f; }
    __syncthreads();
#pragma unroll
    for (int c = 0; c < 4; c++) {
        float s = 0.f, q = 0.f;
#pragma unroll
        for (int j = 0; j < 4; j++) { s += acc[j][c]; q += acc[j][c] * acc[j][c]; }
        atomicAdd(&csum[c0 + c], s);
        atomicAdd(&csq[c0 + c], q);
    }
    __syncthreads();
    if (tid < 128) {
        atomicAdd(&stats[tid],       csum[tid]);
        atomicAdd(&stats[128 + tid], csq[tid]);
    }
}

// ---------------------------------------------------------------------------
extern "C" void kernel_launch(void* const* d_in, const int* in_sizes, int n_in,
                              void* d_out, int out_size, void* d_ws, size_t ws_size,
                              hipStream_t stream)
{
    const float* x     = (const float*)d_in[0];
    const int*   esrc  = (const int*)d_in[1];
    const int*   edst  = (const int*)d_in[2];
    const float* evals = (const float*)d_in[3];
    const float* W     = (const float*)d_in[4];
    // d_in[5] = bias: unused — cancels exactly under BatchNorm.
    const float* gamma = (const float*)d_in[6];
    const float* beta  = (const float*)d_in[7];
    float* out = (float*)d_out;

    const int n = in_sizes[0] / D;   // 100000
    const int E = in_sizes[1];       // 1600000

    const int B     = (n + BROWS - 1) >> BSHIFT;   // 196 buckets
    const int nwgA  = (E + TILE - 1) / TILE;       // 196 tiles
    const int ngemm = (n + 31) / 32;               // 3125 gemm blocks

    // Workspace (word-indexed):
    //   yb      [n*64]            25.6 MB (packed bf16 y = x@W)
    //   stats   [256]             zeroed (1KB memset)
    //   ofs_t   [(B+1)*nwgA]      ~155 KB (transposed: [bucket][wg])
    //   rowptr  [n]
    //   (pad to even word)
    //   slices  uint2[nwgA*TILE]  12.85 MB
    //   csr     ull  [E]          12.8 MB
    unsigned* yb     = (unsigned*)d_ws;
    float*    stats  = (float*)(yb + (size_t)n * 64);
    int*      ofs_t  = (int*)(stats + 256);
    int*      rowptr = ofs_t + (size_t)(B + 1) * nwgA;
    size_t    w_off  = (size_t)n * 64 + 256 + (size_t)(B + 1) * nwgA + n;
    w_off += (w_off & 1);                          // 8B alignment
    uint2*    slices = (uint2*)((unsigned*)d_ws + w_off);
    ull*      csr    = (ull*)(slices + (size_t)nwgA * TILE);
    const size_t need = (w_off + (size_t)nwgA * TILE * 2 + (size_t)E * 2) * 4;

    if (ws_size >= need && B <= 256 && nwgA <= 256) {
        hipMemsetAsync(stats, 0, 256 * 4, stream);
        phase1_kernel<<<nwgA + ngemm, 256, 0, stream>>>(
            x, W, yb, n, esrc, edst, evals, slices, ofs_t, B, nwgA, E);
        binB_kernel<<<B, 1024, 0, stream>>>(
            slices, ofs_t, rowptr, csr, B, nwgA, n);
        spmm_stats_kernel<<<(n + 63) / 64, 256, 0, stream>>>(
            yb, rowptr, csr, out, stats, n);
        bn_apply_kernel<<<2048, 256, 0, stream>>>(out, stats, gamma, beta, n);
    } else {
        // fallback: fp32 atomic-scatter path
        float* agg = (float*)d_ws;
        float* st  = agg + (size_t)n * D;
        hipMemsetAsync(d_ws, 0, ((size_t)n * D + 256) * 4, stream);
        spmm_atomic_kernel<<<4096, 256, 0, stream>>>(x, esrc, edst, evals, agg, E);
        gemm_stats_kernel<<<(n + 31) / 32, 256, 0, stream>>>(agg, W, out, st, n);
        bn_apply_kernel<<<2048, 256, 0, stream>>>(out, st, gamma, beta, n);
    }
}